// Round 11
// baseline (1768.274 us; speedup 1.0000x reference)
//
#include <hip/hip_runtime.h>
#include <hip/hip_bf16.h>
#include <math.h>

typedef __hip_bfloat16 bf16;
typedef short s16x8 __attribute__((ext_vector_type(8)));
typedef float f32x4 __attribute__((ext_vector_type(4)));

__device__ __forceinline__ float b2f(const bf16 v) { return __bfloat162float(v); }
__device__ __forceinline__ float ldf(int isbf, const void* p, size_t i) {
    return isbf ? __bfloat162float(((const bf16*)p)[i]) : ((const float*)p)[i];
}
__device__ __forceinline__ double ldd(int isbf, const void* p, size_t i) {
    return (double)ldf(isbf, p, i);
}
__device__ __forceinline__ short sbf(float f) {
    bf16 h = __float2bfloat16(f);
    return *(short*)&h;
}
__device__ __forceinline__ s16x8 cvt8(float4 a, float4 b) {
    union { bf16 h[8]; s16x8 v; } u;
    u.h[0] = __float2bfloat16(a.x); u.h[1] = __float2bfloat16(a.y);
    u.h[2] = __float2bfloat16(a.z); u.h[3] = __float2bfloat16(a.w);
    u.h[4] = __float2bfloat16(b.x); u.h[5] = __float2bfloat16(b.y);
    u.h[6] = __float2bfloat16(b.z); u.h[7] = __float2bfloat16(b.w);
    return u.v;
}

#define TLEN   64000
#define NMEL   80
#define CHUNK  160            // one frame per chunk
#define NCHK   400
#define SEQ    2560
#define DMODEL 256
#define PI_D   3.14159265358979323846
#define CLW    420            // channels-last padded W dim

// ---- workspace layout (float offsets; double regions 8B-aligned) ----
#define F_COEF  0ul
#define F_FLAG  2560ul
#define F_M     2576ul
#define F_V     12816ul
#define F_INI   524816ul
#define F_FEATS 1036816ul
#define F_TOK   1068816ul
#define F_BIG   1724176ul
#define O_C1CL  0ul
#define O_C2CL  1102080ul
#define O_C3    3306240ul
#define O_WTB2  11500000ul
#define O_WTB3  11540000ul

__global__ void k_detect(const unsigned short* __restrict__ g, int* __restrict__ flag) {
    if (threadIdx.x == 0 && blockIdx.x == 0) *flag = (g[0] == 0x3F80) ? 1 : 0;
}

__global__ void k_coeffs(double* __restrict__ cf) {
    int i = blockIdx.x * 256 + threadIdx.x;
    if (i >= 4 * NMEL) return;
    int s = i / NMEL, m = i % NMEL;
    double lg0 = log10(80.0), lg1 = log10(8000.0);
    double fc = pow(10.0, lg0 + (lg1 - lg0) * (double)m / 79.0);
    double q = 4.0 + 2.0 * (double)s;
    double omega = 2.0 * PI_D * fc / 16000.0;
    double al = sin(omega) / (2.0 * q);
    double a0 = 1.0 + al;
    cf[i * 4 + 0] = (double)(float)(al / a0);
    cf[i * 4 + 1] = (double)(float)(-al / a0);
    cf[i * 4 + 2] = (double)(float)(-2.0 * cos(omega) / a0);
    cf[i * 4 + 3] = (double)(float)((1.0 - al) / a0);
}

// ---- fused-cascade zero-state pass: thread (j,m) -> v[m][j][8] ----
__global__ __launch_bounds__(256) void k_bqf_zero(const void* __restrict__ x,
        const double* __restrict__ cf, const int* __restrict__ flagp,
        double* __restrict__ v) {
    int i = blockIdx.x * 256 + threadIdx.x;
    if (i >= NMEL * NCHK) return;
    int isbf = *flagp;
    int j = i / NMEL, m = i % NMEL;
    double b0[4], b2[4], a1[4], a2[4];
#pragma unroll
    for (int s = 0; s < 4; ++s) {
        const double* c = &cf[(s * NMEL + m) * 4];
        b0[s] = c[0]; b2[s] = c[1]; a1[s] = c[2]; a2[s] = c[3];
    }
    int t0 = j * CHUNK;
    double x1 = (t0 > 0) ? ldd(isbf, x, t0 - 1) : 0.0;
    double x2 = (t0 > 1) ? ldd(isbf, x, t0 - 2) : 0.0;
    double s0 = 0, s1 = 0, s2 = 0, s3 = 0, s4 = 0, s5 = 0, s6 = 0, s7 = 0;
    for (int t = t0; t < t0 + CHUNK; ++t) {
        double xt = ldd(isbf, x, t);
        double y0 = fma(b0[0], xt, fma(b2[0], x2, fma(-a1[0], s0, -a2[0] * s1)));
        double y1 = fma(b0[1], y0, fma(b2[1], s1, fma(-a1[1], s2, -a2[1] * s3)));
        double y2 = fma(b0[2], y1, fma(b2[2], s3, fma(-a1[2], s4, -a2[2] * s5)));
        double y3 = fma(b0[3], y2, fma(b2[3], s5, fma(-a1[3], s6, -a2[3] * s7)));
        s1 = s0; s0 = y0; s3 = s2; s2 = y1; s5 = s4; s4 = y2; s7 = s6; s6 = y3;
        x2 = x1; x1 = xt;
    }
    double* vp = &v[((size_t)m * NCHK + j) * 8];
    vp[0] = s0; vp[1] = s1; vp[2] = s2; vp[3] = s3;
    vp[4] = s4; vp[5] = s5; vp[6] = s6; vp[7] = s7;
}

__global__ __launch_bounds__(256) void k_bqA(const double* __restrict__ cf,
                                             double* __restrict__ M) {
    __shared__ double P[4][8][8], R[4][8][8], T[4][8][8];
    int t = threadIdx.x;
    int cg = t >> 6, e8 = t & 63;
    int i = e8 >> 3, jj = e8 & 7;
    int m = blockIdx.x * 4 + cg;
    double b0[4], b2[4], a1[4], a2[4];
#pragma unroll
    for (int s = 0; s < 4; ++s) {
        const double* c = &cf[(s * NMEL + m) * 4];
        b0[s] = c[0]; b2[s] = c[1]; a1[s] = c[2]; a2[s] = c[3];
    }
    double s[8];
#pragma unroll
    for (int k = 0; k < 8; ++k) s[k] = (k == jj) ? 1.0 : 0.0;
    double y0 = fma(-a1[0], s[0], -a2[0] * s[1]);
    double y1 = fma(b0[1], y0, fma(b2[1], s[1], fma(-a1[1], s[2], -a2[1] * s[3])));
    double y2 = fma(b0[2], y1, fma(b2[2], s[3], fma(-a1[2], s[4], -a2[2] * s[5])));
    double y3 = fma(b0[3], y2, fma(b2[3], s[5], fma(-a1[3], s[6], -a2[3] * s[7])));
    double colv[8] = {y0, s[0], y1, s[2], y2, s[4], y3, s[6]};
    P[cg][i][jj] = colv[i];
    R[cg][i][jj] = (i == jj) ? 1.0 : 0.0;
    __syncthreads();
    int e = CHUNK;
    while (e) {
        double acc = 0.0;
#pragma unroll
        for (int k = 0; k < 8; ++k) acc = fma(R[cg][i][k], P[cg][k][jj], acc);
        T[cg][i][jj] = acc;
        __syncthreads();
        if (e & 1) R[cg][i][jj] = T[cg][i][jj];
        __syncthreads();
        acc = 0.0;
#pragma unroll
        for (int k = 0; k < 8; ++k) acc = fma(P[cg][i][k], P[cg][k][jj], acc);
        T[cg][i][jj] = acc;
        __syncthreads();
        P[cg][i][jj] = T[cg][i][jj];
        e >>= 1;
        __syncthreads();
    }
    M[(size_t)m * 64 + i * 8 + jj] = R[cg][i][jj];
}

// ---- Kogge-Stone parallel chunk scan (NCHK=400, 9 steps); block = channel ----
__global__ __launch_bounds__(512) void k_bq_scan8p(const double* __restrict__ Mbuf,
        const double* __restrict__ v, double* __restrict__ ini) {
    __shared__ double Mp[9][64];
    __shared__ double bufA[NCHK][8];
    __shared__ double bufB[NCHK][8];
    int m = blockIdx.x, t = threadIdx.x;
    if (t < 64) Mp[0][t] = Mbuf[(size_t)m * 64 + t];
    __syncthreads();
    for (int s = 1; s < 9; ++s) {
        if (t < 64) {
            int i = t >> 3, jj = t & 7;
            double acc = 0.0;
#pragma unroll
            for (int k = 0; k < 8; ++k) acc = fma(Mp[s - 1][i * 8 + k], Mp[s - 1][k * 8 + jj], acc);
            Mp[s][t] = acc;
        }
        __syncthreads();
    }
    double b[8];
    if (t < NCHK) {
        const double* vp = &v[((size_t)m * NCHK + t) * 8];
#pragma unroll
        for (int i = 0; i < 8; ++i) { b[i] = vp[i]; bufA[t][i] = b[i]; }
    }
    __syncthreads();
#pragma unroll
    for (int s = 0; s < 9; ++s) {
        int off = 1 << s;
        double nb[8];
        if (t < NCHK) {
            if (t >= off) {
                const double* src = (s & 1) ? bufB[t - off] : bufA[t - off];
#pragma unroll
                for (int i = 0; i < 8; ++i) {
                    double acc = b[i];
#pragma unroll
                    for (int k = 0; k < 8; ++k) acc = fma(Mp[s][i * 8 + k], src[k], acc);
                    nb[i] = acc;
                }
            } else {
#pragma unroll
                for (int i = 0; i < 8; ++i) nb[i] = b[i];
            }
        }
        __syncthreads();
        if (t < NCHK) {
            double* dst = (s & 1) ? bufA[t] : bufB[t];
#pragma unroll
            for (int i = 0; i < 8; ++i) { dst[i] = nb[i]; b[i] = nb[i]; }
        }
        __syncthreads();
    }
    if (t < NCHK) {
        double* op = &ini[((size_t)m * NCHK + t) * 8];
        if (t == 0) {
#pragma unroll
            for (int i = 0; i < 8; ++i) op[i] = 0.0;
        } else {
#pragma unroll
            for (int i = 0; i < 8; ++i) op[i] = bufB[t - 1][i];
        }
    }
}

// ---- fused-cascade emit: 1 frame/thread -> |y3| mean -> log -> feats ----
__global__ __launch_bounds__(256) void k_bqf_emit(const void* __restrict__ x,
        const double* __restrict__ cf, const int* __restrict__ flagp,
        const double* __restrict__ ini, float* __restrict__ feats) {
    int i = blockIdx.x * 256 + threadIdx.x;
    if (i >= NMEL * NCHK) return;
    int isbf = *flagp;
    int j = i / NMEL, m = i % NMEL;
    double b0[4], b2[4], a1[4], a2[4];
#pragma unroll
    for (int s = 0; s < 4; ++s) {
        const double* c = &cf[(s * NMEL + m) * 4];
        b0[s] = c[0]; b2[s] = c[1]; a1[s] = c[2]; a2[s] = c[3];
    }
    int t0 = j * CHUNK;
    double x1 = (t0 > 0) ? ldd(isbf, x, t0 - 1) : 0.0;
    double x2 = (t0 > 1) ? ldd(isbf, x, t0 - 2) : 0.0;
    const double* ip = &ini[((size_t)m * NCHK + j) * 8];
    double s0 = ip[0], s1 = ip[1], s2 = ip[2], s3 = ip[3];
    double s4 = ip[4], s5 = ip[5], s6 = ip[6], s7 = ip[7];
    double acc = 0.0;
    for (int t = t0; t < t0 + CHUNK; ++t) {
        double xt = ldd(isbf, x, t);
        double y0 = fma(b0[0], xt, fma(b2[0], x2, fma(-a1[0], s0, -a2[0] * s1)));
        double y1 = fma(b0[1], y0, fma(b2[1], s1, fma(-a1[1], s2, -a2[1] * s3)));
        double y2 = fma(b0[2], y1, fma(b2[2], s3, fma(-a1[2], s4, -a2[2] * s5)));
        double y3 = fma(b0[3], y2, fma(b2[3], s5, fma(-a1[3], s6, -a2[3] * s7)));
        acc += fabs(y3);
        s1 = s0; s0 = y0; s3 = s2; s2 = y1; s5 = s4; s4 = y2; s7 = s6; s6 = y3;
        x2 = x1; x1 = xt;
    }
    feats[(size_t)m * 400 + j] = (float)log(acc * (1.0 / 160.0) + 1e-8);
}

__global__ void k_fill0(bf16* __restrict__ p, int n8) {
    int i = blockIdx.x * 256 + threadIdx.x;
    if (i < n8) { s16x8 z = {}; ((s16x8*)p)[i] = z; }
}

__global__ void k_wtb(const void* __restrict__ w, const int* __restrict__ flagp,
                      bf16* __restrict__ out, int CO, int CIN) {
    int i = blockIdx.x * 256 + threadIdx.x;
    int K = CIN * 9;
    if (i >= CO * K) return;
    int co = i / K, rem = i % K;
    int c = rem / 288, tp = (rem / 32) % 9, cin = rem & 31;
    out[i] = __float2bfloat16(ldf(*flagp, w, ((size_t)co * CIN + c * 32 + cin) * 9 + tp));
}

__global__ __launch_bounds__(256) void k_conv1cl(const float* __restrict__ in,
        const void* __restrict__ wt, const void* __restrict__ bi,
        const void* __restrict__ ga, const void* __restrict__ be,
        const int* __restrict__ flagp, bf16* __restrict__ out) {
    __shared__ float wsh[576];
    __shared__ float ash[64];
    __shared__ float bsh[64];
    int t = threadIdx.x;
    int isbf = *flagp;
    for (int i = t; i < 576; i += 256) wsh[i] = ldf(isbf, wt, i);
    if (t < 64) {
        float A = ldf(isbf, ga, t) * 0.999995000037f;
        ash[t] = A;
        bsh[t] = fmaf(ldf(isbf, bi, t), A, ldf(isbf, be, t));
    }
    __syncthreads();
    int i = blockIdx.x * 256 + t;
    if (i >= 32000) return;
    int h = i / 400, w = i % 400;
    float xs[9];
#pragma unroll
    for (int dy = 0; dy < 3; ++dy)
#pragma unroll
        for (int dx = 0; dx < 3; ++dx) {
            int hh = h + dy - 1, ww = w + dx - 1;
            xs[dy * 3 + dx] = (hh >= 0 && hh < 80 && ww >= 0 && ww < 400)
                              ? in[hh * 400 + ww] : 0.f;
        }
    bf16* op = out + ((size_t)(h + 1) * CLW + (w + 1)) * 64;
#pragma unroll
    for (int g = 0; g < 8; ++g) {
        union { bf16 h8[8]; s16x8 v; } u;
#pragma unroll
        for (int e = 0; e < 8; ++e) {
            int co = g * 8 + e;
            float acc = 0.f;
#pragma unroll
            for (int uu = 0; uu < 9; ++uu) acc = fmaf(wsh[co * 9 + uu], xs[uu], acc);
            u.h8[e] = __float2bfloat16(fmaxf(fmaf(acc, ash[co], bsh[co]), 0.f));
        }
        *(s16x8*)&op[g * 8] = u.v;
    }
}

// ---- MFMA conv3x3, 2 output rows per block: in [82][420][CIN] bf16 padded CL ----
// grid (13, 40); block 256 = 4 waves; block covers all CO x 32 w x 2 h.
template<int CIN, int CO, int CLOUT>
__global__ __launch_bounds__(256) void k_convm(const bf16* __restrict__ cl,
        const bf16* __restrict__ Wtb,
        const void* __restrict__ bi, const void* __restrict__ ga,
        const void* __restrict__ be, const int* __restrict__ flagp,
        void* __restrict__ out) {
    const int MT = CO / 64;
    const int K = CIN * 9;
    __shared__ short Bs[4][36][40];
    int t = threadIdx.x, wv = t >> 6, L = t & 63, quad = L >> 4, lx = L & 15;
    int w0 = blockIdx.x * 32, h0 = blockIdx.y * 2;
    int cob = wv * (CO / 4);
    f32x4 acc[MT][2][2] = {};     // [mt][hr][n]
    for (int c = 0; c < CIN / 32; ++c) {
        __syncthreads();
        // stage 4 dy rows x 34 w x 32 ci : 544 stores of 8 bf16
        for (int u = t; u < 544; u += 256) {
            int seg = u >> 2, part = u & 3;
            int dy = seg / 34, ww = seg % 34;
            *(s16x8*)&Bs[dy][ww][part * 8] =
                *(const s16x8*)&cl[((size_t)(h0 + dy) * CLW + (w0 + ww)) * CIN + c * 32 + part * 8];
        }
        __syncthreads();
#pragma unroll
        for (int tp = 0; tp < 9; ++tp) {
            int dy = tp / 3, dx = tp % 3;
            int kbase = (c * 9 + tp) * 32;
            s16x8 af[MT];
#pragma unroll
            for (int mt = 0; mt < MT; ++mt)
                af[mt] = *(const s16x8*)&Wtb[(size_t)(cob + mt * 16 + lx) * K + kbase + quad * 8];
#pragma unroll
            for (int hr = 0; hr < 2; ++hr) {
#pragma unroll
                for (int n = 0; n < 2; ++n) {
                    s16x8 bfr = *(const s16x8*)&Bs[dy + hr][n * 16 + lx + dx][quad * 8];
#pragma unroll
                    for (int mt = 0; mt < MT; ++mt)
                        acc[mt][hr][n] = __builtin_amdgcn_mfma_f32_16x16x32_bf16(af[mt], bfr, acc[mt][hr][n], 0, 0, 0);
                }
            }
        }
    }
    int isbf = *flagp;
#pragma unroll
    for (int mt = 0; mt < MT; ++mt) {
#pragma unroll
        for (int r = 0; r < 4; ++r) {
            int co = cob + mt * 16 + quad * 4 + r;
            float A = ldf(isbf, ga, co) * 0.999995000037f;
            float B = fmaf(ldf(isbf, bi, co), A, ldf(isbf, be, co));
#pragma unroll
            for (int hr = 0; hr < 2; ++hr) {
                int h = h0 + hr;
#pragma unroll
                for (int n = 0; n < 2; ++n) {
                    int w = w0 + n * 16 + lx;
                    if (w < 400) {
                        float v = fmaxf(fmaf(acc[mt][hr][n][r], A, B), 0.f);
                        if (CLOUT)
                            ((bf16*)out)[((size_t)(h + 1) * CLW + (w + 1)) * CO + co] = __float2bfloat16(v);
                        else
                            ((float*)out)[(size_t)co * 32000 + h * 400 + w] = v;
                    }
                }
            }
        }
    }
}

__global__ __launch_bounds__(256) void k_pool(const float* __restrict__ c3,
                                              float* __restrict__ tok) {
    int i = blockIdx.x * 256 + threadIdx.x;
    if (i >= SEQ * DMODEL) return;
    int s = i >> 8, c = i & 255;
    int f = s >> 5, jj = s & 31;
    int w0 = (jj * 25) >> 1;
    const float* p = c3 + ((size_t)c * 80 + f) * 400 + w0;
    float sum = 0.f;
#pragma unroll
    for (int k = 0; k < 13; ++k) sum += p[k];
    tok[i] = sum * (1.f / 13.f);
}

// ===== MFMA bf16 GEMM, chunked-K staging (KC=128): 4*NT mfma per barrier-pair =====
// OUTMODE: 0 fp32 ; 1 flex ; 2 bf16 + V^T side-copy ; 3 always bf16
template<int RELU, int OUTMODE, int NT, int ACOMB>
__global__ __launch_bounds__(256) void k_gemm(const float* __restrict__ A,
        const void* __restrict__ W, size_t woff,
        const void* __restrict__ bias, size_t boff,
        const int* __restrict__ flagp, void* __restrict__ Cout_,
        bf16* __restrict__ vtb, const float* __restrict__ partb,
        int M, int N, int K) {
    __shared__ short As[64][136];
    __shared__ short Bs[NT * 16][136];
    const int isbf = *flagp;
    int t = threadIdx.x;
    int wv = t >> 6, L = t & 63, quad = L >> 4, lx = L & 15;
    int row0 = blockIdx.y * 64, col0 = blockIdx.x * (NT * 16);
    f32x4 acc[NT] = {};
    for (int k0 = 0; k0 < K; k0 += 128) {
        __syncthreads();
        {
            int row = t >> 2, cb = (t & 3) * 8;
#pragma unroll
            for (int c = 0; c < 4; ++c) {
                int col = cb + c * 32;
                s16x8 av;
                if (ACOMB) {
                    int q = row0 + row;
                    int kk = k0 + col;
                    int hh = kk >> 5, d = kk & 31;
                    const float* pa = partb + ((size_t)(hh * 2) * SEQ + q) * 36;
                    const float* pc = pa + (size_t)SEQ * 36;
                    float m0 = pa[32], l0 = pa[33], m1 = pc[32], l1 = pc[33];
                    float Mx = fmaxf(m0, m1);
                    float e0 = __expf(m0 - Mx), e1 = __expf(m1 - Mx);
                    float inv = 1.f / (l0 * e0 + l1 * e1);
                    float4 u0 = *(const float4*)(pa + d), u1 = *(const float4*)(pa + d + 4);
                    float4 v0 = *(const float4*)(pc + d), v1 = *(const float4*)(pc + d + 4);
                    float4 r0, r1;
                    r0.x = (u0.x * e0 + v0.x * e1) * inv; r0.y = (u0.y * e0 + v0.y * e1) * inv;
                    r0.z = (u0.z * e0 + v0.z * e1) * inv; r0.w = (u0.w * e0 + v0.w * e1) * inv;
                    r1.x = (u1.x * e0 + v1.x * e1) * inv; r1.y = (u1.y * e0 + v1.y * e1) * inv;
                    r1.z = (u1.z * e0 + v1.z * e1) * inv; r1.w = (u1.w * e0 + v1.w * e1) * inv;
                    av = cvt8(r0, r1);
                } else {
                    const float* ap = &A[(size_t)(row0 + row) * K + k0 + col];
                    av = cvt8(*(const float4*)ap, *(const float4*)(ap + 4));
                }
                *(s16x8*)&As[row][col] = av;
            }
        }
        if (NT == 4) {
            int row = t >> 2, cb = (t & 3) * 8;
#pragma unroll
            for (int c = 0; c < 4; ++c) {
                int col = cb + c * 32;
                size_t widx = woff + (size_t)(col0 + row) * K + k0 + col;
                s16x8 wv8;
                if (isbf) {
                    wv8 = *(const s16x8*)((const bf16*)W + widx);
                } else {
                    const float* wf = (const float*)W + widx;
                    wv8 = cvt8(*(const float4*)wf, *(const float4*)(wf + 4));
                }
                *(s16x8*)&Bs[row][col] = wv8;
            }
        } else {
            int row = t >> 3, cb = (t & 7) * 8;
#pragma unroll
            for (int c = 0; c < 2; ++c) {
                int col = cb + c * 64;
                size_t widx = woff + (size_t)(col0 + row) * K + k0 + col;
                s16x8 wv8;
                if (isbf) {
                    wv8 = *(const s16x8*)((const bf16*)W + widx);
                } else {
                    const float* wf = (const float*)W + widx;
                    wv8 = cvt8(*(const float4*)wf, *(const float4*)(wf + 4));
                }
                *(s16x8*)&Bs[row][col] = wv8;
            }
        }
        __syncthreads();
#pragma unroll
        for (int kc = 0; kc < 4; ++kc) {
            s16x8 af = *(const s16x8*)&As[wv * 16 + lx][kc * 32 + quad * 8];
#pragma unroll
            for (int n = 0; n < NT; ++n) {
                s16x8 bf_ = *(const s16x8*)&Bs[n * 16 + lx][kc * 32 + quad * 8];
                acc[n] = __builtin_amdgcn_mfma_f32_16x16x32_bf16(af, bf_, acc[n], 0, 0, 0);
            }
        }
    }
#pragma unroll
    for (int n = 0; n < NT; ++n) {
        int col = col0 + n * 16 + lx;
        float bv = ldf(isbf, bias, boff + col);
#pragma unroll
        for (int r = 0; r < 4; ++r) {
            int row = row0 + wv * 16 + quad * 4 + r;
            float val = acc[n][r] + bv;
            if (RELU) val = fmaxf(val, 0.f);
            if (OUTMODE == 0) {
                ((float*)Cout_)[(size_t)row * N + col] = val;
            } else if (OUTMODE == 2) {
                bf16 bb_ = __float2bfloat16(val);
                ((bf16*)Cout_)[(size_t)row * N + col] = bb_;
                if (col >= 512) vtb[(size_t)(col - 512) * SEQ + row] = bb_;
            } else if (OUTMODE == 3) {
                ((bf16*)Cout_)[(size_t)row * N + col] = __float2bfloat16(val);
            } else {
                if (isbf) ((bf16*)Cout_)[(size_t)row * N + col] = __float2bfloat16(val);
                else      ((float*)Cout_)[(size_t)row * N + col] = val;
            }
        }
    }
}

// ===== fused GEMM (N=256) + bias + residual + LayerNorm, in-place on tok =====
// grid: M/64 blocks; wave = 16 rows x 256 cols (16 n-tiles); K chunked by 64.
// ABF16: A is bf16 ; ACOMB: A = softmax-combined attention partials.
template<int ABF16, int ACOMB>
__global__ __launch_bounds__(256) void k_gemmln(const void* __restrict__ A,
        const void* __restrict__ W, size_t woff,
        const void* __restrict__ bias, size_t boff,
        const void* __restrict__ gg, const void* __restrict__ bb, size_t goff,
        const int* __restrict__ flagp, float* __restrict__ tok,
        const float* __restrict__ partb, int K) {
    __shared__ short As[64][72];
    __shared__ short Bs[256][72];
    const int isbf = *flagp;
    int t = threadIdx.x;
    int wv = t >> 6, L = t & 63, quad = L >> 4, lx = L & 15;
    int row0 = blockIdx.x * 64;
    f32x4 acc[16] = {};
    for (int k0 = 0; k0 < K; k0 += 64) {
        __syncthreads();
        {   // stage A: 64 rows x 64 k
            int row = t >> 2, cb = (t & 3) * 16;
#pragma unroll
            for (int c = 0; c < 2; ++c) {
                int col = cb + c * 8;
                s16x8 av;
                if (ACOMB) {
                    int q = row0 + row;
                    int kk = k0 + col;
                    int hh = kk >> 5, d = kk & 31;
                    const float* pa = partb + ((size_t)(hh * 2) * SEQ + q) * 36;
                    const float* pc = pa + (size_t)SEQ * 36;
                    float m0 = pa[32], l0 = pa[33], m1 = pc[32], l1 = pc[33];
                    float Mx = fmaxf(m0, m1);
                    float e0 = __expf(m0 - Mx), e1 = __expf(m1 - Mx);
                    float inv = 1.f / (l0 * e0 + l1 * e1);
                    float4 u0 = *(const float4*)(pa + d), u1 = *(const float4*)(pa + d + 4);
                    float4 v0 = *(const float4*)(pc + d), v1 = *(const float4*)(pc + d + 4);
                    float4 r0, r1;
                    r0.x = (u0.x * e0 + v0.x * e1) * inv; r0.y = (u0.y * e0 + v0.y * e1) * inv;
                    r0.z = (u0.z * e0 + v0.z * e1) * inv; r0.w = (u0.w * e0 + v0.w * e1) * inv;
                    r1.x = (u1.x * e0 + v1.x * e1) * inv; r1.y = (u1.y * e0 + v1.y * e1) * inv;
                    r1.z = (u1.z * e0 + v1.z * e1) * inv; r1.w = (u1.w * e0 + v1.w * e1) * inv;
                    av = cvt8(r0, r1);
                } else if (ABF16) {
                    av = *(const s16x8*)((const bf16*)A + (size_t)(row0 + row) * K + k0 + col);
                } else {
                    const float* ap = (const float*)A + (size_t)(row0 + row) * K + k0 + col;
                    av = cvt8(*(const float4*)ap, *(const float4*)(ap + 4));
                }
                *(s16x8*)&As[row][col] = av;
            }
        }
        {   // stage B: 256 n-rows x 64 k (thread t = W row t)
#pragma unroll
            for (int c = 0; c < 8; ++c) {
                int col = c * 8;
                size_t widx = woff + (size_t)t * K + k0 + col;
                s16x8 wv8;
                if (isbf) {
                    wv8 = *(const s16x8*)((const bf16*)W + widx);
                } else {
                    const float* wf = (const float*)W + widx;
                    wv8 = cvt8(*(const float4*)wf, *(const float4*)(wf + 4));
                }
                *(s16x8*)&Bs[t][col] = wv8;
            }
        }
        __syncthreads();
#pragma unroll
        for (int kc = 0; kc < 2; ++kc) {
            s16x8 af = *(const s16x8*)&As[wv * 16 + lx][kc * 32 + quad * 8];
#pragma unroll
            for (int n = 0; n < 16; ++n) {
                s16x8 bf_ = *(const s16x8*)&Bs[n * 16 + lx][kc * 32 + quad * 8];
                acc[n] = __builtin_amdgcn_mfma_f32_16x16x32_bf16(af, bf_, acc[n], 0, 0, 0);
            }
        }
    }
    // ---- epilogue: bias + residual + LayerNorm per row ----
#pragma unroll
    for (int r = 0; r < 4; ++r) {
        int row = row0 + wv * 16 + quad * 4 + r;
        float* tp = tok + (size_t)row * DMODEL;
        float vals[16];
        float s = 0.f;
#pragma unroll
        for (int n = 0; n < 16; ++n) {
            int col = n * 16 + lx;
            float v = acc[n][r] + ldf(isbf, bias, boff + col) + tp[col];
            vals[n] = v; s += v;
        }
#pragma unroll
        for (int mk = 1; mk < 16; mk <<= 1) s += __shfl_xor(s, mk);
        float mean = s * (1.f / 256.f);
        float vs = 0.f;
#pragma unroll
        for (int n = 0; n < 16; ++n) { float d = vals[n] - mean; vs += d * d; }
#pragma unroll
        for (int mk = 1; mk < 16; mk <<= 1) vs += __shfl_xor(vs, mk);
        float rstd = rsqrtf(vs * (1.f / 256.f) + 1e-5f);
#pragma unroll
        for (int n = 0; n < 16; ++n) {
            int col = n * 16 + lx;
            tp[col] = fmaf((vals[n] - mean) * rstd, ldf(isbf, gg, goff + col),
                           ldf(isbf, bb, goff + col));
        }
    }
}

// ===== MFMA flash attention, KSPLIT=2; part rows stride 36 =====
__global__ __launch_bounds__(256) void k_flash(const bf16* __restrict__ qkvB,
        const bf16* __restrict__ vtb, float* __restrict__ part) {
    int b = blockIdx.x;
    int pp = b & 1, qb = (b >> 1) % 40, h = b / 80;
    int t = threadIdx.x, wv = t >> 6, L = t & 63, quad = L >> 4, lx = L & 15;
    int q0 = qb * 64;
    __shared__ short Qs[64][40];
    __shared__ short Ks[64][40];
    __shared__ short Vt[32][72];
    __shared__ short Ps[64][72];
    const float scale = 0.17677669529663687f;
    int sr = t >> 2, sk = (t & 3) * 8;
    *(s16x8*)&Qs[sr][sk] = *(const s16x8*)&qkvB[(size_t)(q0 + sr) * 768 + h * 32 + sk];
    f32x4 o[2] = {};
    float mrow[4], lrow[4];
#pragma unroll
    for (int r = 0; r < 4; ++r) { mrow[r] = -INFINITY; lrow[r] = 0.f; }
    int kstart = pp * 1280;
    int vd = t >> 3, vk = (t & 7) * 8;
    for (int kt = 0; kt < 20; ++kt) {
        int kb = kstart + kt * 64;
        __syncthreads();
        *(s16x8*)&Ks[sr][sk] = *(const s16x8*)&qkvB[(size_t)(kb + sr) * 768 + 256 + h * 32 + sk];
        *(s16x8*)&Vt[vd][vk] = *(const s16x8*)&vtb[(size_t)(h * 32 + vd) * SEQ + kb + vk];
        __syncthreads();
        s16x8 qf = *(const s16x8*)&Qs[wv * 16 + lx][quad * 8];
        f32x4 sc[4] = {};
#pragma unroll
        for (int n = 0; n < 4; ++n) {
            s16x8 kf = *(const s16x8*)&Ks[n * 16 + lx][quad * 8];
            sc[n] = __builtin_amdgcn_mfma_f32_16x16x32_bf16(qf, kf, sc[n], 0, 0, 0);
        }
#pragma unroll
        for (int r = 0; r < 4; ++r) {
            float tm = -INFINITY;
#pragma unroll
            for (int n = 0; n < 4; ++n) { sc[n][r] *= scale; tm = fmaxf(tm, sc[n][r]); }
#pragma unroll
            for (int mk = 1; mk < 16; mk <<= 1) tm = fmaxf(tm, __shfl_xor(tm, mk));
            float mn = fmaxf(mrow[r], tm);
            float al = __expf(mrow[r] - mn);
            float ps = 0.f;
#pragma unroll
            for (int n = 0; n < 4; ++n) {
                float e = __expf(sc[n][r] - mn);
                sc[n][r] = e; ps += e;
            }
#pragma unroll
            for (int mk = 1; mk < 16; mk <<= 1) ps += __shfl_xor(ps, mk);
            lrow[r] = lrow[r] * al + ps;
            mrow[r] = mn;
            o[0][r] *= al; o[1][r] *= al;
            int qrow = wv * 16 + quad * 4 + r;
#pragma unroll
            for (int n = 0; n < 4; ++n) Ps[qrow][n * 16 + lx] = sbf(sc[n][r]);
        }
        __syncthreads();
#pragma unroll
        for (int ks = 0; ks < 2; ++ks) {
            s16x8 pf = *(const s16x8*)&Ps[wv * 16 + lx][ks * 32 + quad * 8];
#pragma unroll
            for (int n = 0; n < 2; ++n) {
                s16x8 vf = *(const s16x8*)&Vt[n * 16 + lx][ks * 32 + quad * 8];
                o[n] = __builtin_amdgcn_mfma_f32_16x16x32_bf16(pf, vf, o[n], 0, 0, 0);
            }
        }
    }
#pragma unroll
    for (int r = 0; r < 4; ++r) {
        int q = q0 + wv * 16 + quad * 4 + r;
        size_t pb_ = ((size_t)(h * 2 + pp) * SEQ + q) * 36;
        part[pb_ + lx] = o[0][r];
        part[pb_ + 16 + lx] = o[1][r];
        if (lx == 0) { part[pb_ + 32] = mrow[r]; part[pb_ + 33] = lrow[r]; }
    }
}

extern "C" void kernel_launch(void* const* d_in, const int* in_sizes, int n_in,
                              void* d_out, int out_size, void* d_ws, size_t ws_size,
                              hipStream_t stream) {
    const void* x    = d_in[0];
    const void* cw1  = d_in[1];  const void* cb1 = d_in[2];
    const void* g1   = d_in[3];  const void* be1 = d_in[4];
    const void* cw2  = d_in[5];  const void* cb2 = d_in[6];
    const void* g2   = d_in[7];  const void* be2 = d_in[8];
    const void* cw3  = d_in[9];  const void* cb3 = d_in[10];
    const void* g3   = d_in[11]; const void* be3 = d_in[12];
    const void* qkvw = d_in[13]; const void* qkvb = d_in[14];
    const void* outw = d_in[15]; const void* outb = d_in[16];
    const void* ln1g = d_in[17]; const void* ln1b = d_in[18];
    const void* ff1w = d_in[19]; const void* ff1b = d_in[20];
    const void* ff2w = d_in[21]; const void* ff2b = d_in[22];
    const void* ln2g = d_in[23]; const void* ln2b = d_in[24];
    const void* pw   = d_in[25]; const void* pb   = d_in[26];

    float*  ws    = (float*)d_ws;
    double* coef  = (double*)(ws + F_COEF);
    int*    flagp = (int*)(ws + F_FLAG);
    double* Mbuf  = (double*)(ws + F_M);
    double* vbuf  = (double*)(ws + F_V);
    double* ini   = (double*)(ws + F_INI);
    float*  feats = ws + F_FEATS;
    float*  tok   = ws + F_TOK;
    bf16*   c1cl  = (bf16*)(ws + F_BIG + O_C1CL);
    bf16*   c2cl  = (bf16*)(ws + F_BIG + O_C2CL);
    float*  c3    = ws + F_BIG + O_C3;
    bf16*   Wtb2  = (bf16*)(ws + F_BIG + O_WTB2);
    bf16*   Wtb3  = (bf16*)(ws + F_BIG + O_WTB3);
    bf16*   qkvB  = (bf16*)(ws + F_BIG);
    bf16*   vtb   = (bf16*)(ws + F_BIG + 983040ul);
    float*  partb = ws + F_BIG + 1310720ul;
    bf16*   ff1bf = (bf16*)(ws + F_BIG + 2785280ul);   // 2560x1024 bf16

    k_detect<<<dim3(1), dim3(64), 0, stream>>>((const unsigned short*)ln1g, flagp);
    k_coeffs<<<dim3(2), dim3(256), 0, stream>>>(coef);
    k_wtb<<<dim3(288), dim3(256), 0, stream>>>(cw2, flagp, Wtb2, 128, 64);
    k_wtb<<<dim3(1152), dim3(256), 0, stream>>>(cw3, flagp, Wtb3, 256, 128);

    // ---- cochlear cascade: fused 4-stage recurrence (fp64), CHUNK = one frame ----
    k_bqA<<<dim3(20), dim3(256), 0, stream>>>(coef, Mbuf);
    k_bqf_zero<<<dim3(125), dim3(256), 0, stream>>>(x, coef, flagp, vbuf);
    k_bq_scan8p<<<dim3(80), dim3(512), 0, stream>>>(Mbuf, vbuf, ini);
    k_bqf_emit<<<dim3(125), dim3(256), 0, stream>>>(x, coef, flagp, ini, feats);

    // ---- conv stack (channels-last MFMA, 2 rows/block) ----
    k_fill0<<<dim3(1077), dim3(256), 0, stream>>>(c1cl, 275520);
    k_fill0<<<dim3(2153), dim3(256), 0, stream>>>(c2cl, 551040);
    k_conv1cl<<<dim3(125), dim3(256), 0, stream>>>(feats, cw1, cb1, g1, be1, flagp, c1cl);
    k_convm<64, 128, 1><<<dim3(13, 40), dim3(256), 0, stream>>>(
        c1cl, Wtb2, cb2, g2, be2, flagp, c2cl);
    k_convm<128, 256, 0><<<dim3(13, 40), dim3(256), 0, stream>>>(
        c2cl, Wtb3, cb3, g3, be3, flagp, c3);

    k_pool<<<dim3(2560), dim3(256), 0, stream>>>(c3, tok);

    // ---- transformer encoder x8 (MFMA bf16; proj+LN and ff2+LN fused) ----
    for (int l = 0; l < 8; ++l) {
        k_gemm<0, 2, 4, 0><<<dim3(12, 40), dim3(256), 0, stream>>>(
            tok, qkvw, (size_t)l * 768 * 256, qkvb, (size_t)l * 768,
            flagp, qkvB, vtb, nullptr, SEQ, 768, 256);
        k_flash<<<dim3(640), dim3(256), 0, stream>>>(qkvB, vtb, partb);
        k_gemmln<0, 1><<<dim3(40), dim3(256), 0, stream>>>(
            nullptr, outw, (size_t)l * 256 * 256, outb, (size_t)l * 256,
            ln1g, ln1b, (size_t)l * 256, flagp, tok, partb, 256);
        k_gemm<1, 3, 4, 0><<<dim3(16, 40), dim3(256), 0, stream>>>(
            tok, ff1w, (size_t)l * 1024 * 256, ff1b, (size_t)l * 1024,
            flagp, ff1bf, nullptr, nullptr, SEQ, 1024, 256);
        k_gemmln<1, 0><<<dim3(40), dim3(256), 0, stream>>>(
            ff1bf, ff2w, (size_t)l * 256 * 1024, ff2b, (size_t)l * 256,
            ln2g, ln2b, (size_t)l * 256, flagp, tok, nullptr, 1024);
    }

    k_gemm<0, 1, 2, 0><<<dim3(16, 40), dim3(256), 0, stream>>>(
        tok, pw, 0ul, pb, 0ul, flagp, d_out, nullptr, nullptr, SEQ, 512, 256);
}

// Round 12
// 1193.661 us; speedup vs baseline: 1.4814x; 1.4814x over previous
//
#include <hip/hip_runtime.h>
#include <hip/hip_bf16.h>
#include <math.h>

typedef __hip_bfloat16 bf16;
typedef short s16x8 __attribute__((ext_vector_type(8)));
typedef float f32x4 __attribute__((ext_vector_type(4)));

__device__ __forceinline__ float b2f(const bf16 v) { return __bfloat162float(v); }
__device__ __forceinline__ float ldf(int isbf, const void* p, size_t i) {
    return isbf ? __bfloat162float(((const bf16*)p)[i]) : ((const float*)p)[i];
}
__device__ __forceinline__ double ldd(int isbf, const void* p, size_t i) {
    return (double)ldf(isbf, p, i);
}
__device__ __forceinline__ short sbf(float f) {
    bf16 h = __float2bfloat16(f);
    return *(short*)&h;
}
__device__ __forceinline__ s16x8 cvt8(float4 a, float4 b) {
    union { bf16 h[8]; s16x8 v; } u;
    u.h[0] = __float2bfloat16(a.x); u.h[1] = __float2bfloat16(a.y);
    u.h[2] = __float2bfloat16(a.z); u.h[3] = __float2bfloat16(a.w);
    u.h[4] = __float2bfloat16(b.x); u.h[5] = __float2bfloat16(b.y);
    u.h[6] = __float2bfloat16(b.z); u.h[7] = __float2bfloat16(b.w);
    return u.v;
}

#define TLEN   64000
#define NMEL   80
#define CHUNK  160            // one frame per chunk
#define NCHK   400
#define SEQ    2560
#define DMODEL 256
#define PI_D   3.14159265358979323846
#define CLW    420            // channels-last padded W dim

// ---- workspace layout (float offsets; double regions 8B-aligned) ----
#define F_COEF  0ul
#define F_FLAG  2560ul
#define F_M     2576ul
#define F_V     12816ul
#define F_INI   524816ul
#define F_FEATS 1036816ul
#define F_TOK   1068816ul
#define F_BIG   1724176ul
#define O_C1CL  0ul
#define O_C2CL  1102080ul
#define O_C3    3306240ul
#define O_WTB2  11500000ul
#define O_WTB3  11540000ul

__global__ void k_detect(const unsigned short* __restrict__ g, int* __restrict__ flag) {
    if (threadIdx.x == 0 && blockIdx.x == 0) *flag = (g[0] == 0x3F80) ? 1 : 0;
}

__global__ void k_coeffs(double* __restrict__ cf) {
    int i = blockIdx.x * 256 + threadIdx.x;
    if (i >= 4 * NMEL) return;
    int s = i / NMEL, m = i % NMEL;
    double lg0 = log10(80.0), lg1 = log10(8000.0);
    double fc = pow(10.0, lg0 + (lg1 - lg0) * (double)m / 79.0);
    double q = 4.0 + 2.0 * (double)s;
    double omega = 2.0 * PI_D * fc / 16000.0;
    double al = sin(omega) / (2.0 * q);
    double a0 = 1.0 + al;
    cf[i * 4 + 0] = (double)(float)(al / a0);
    cf[i * 4 + 1] = (double)(float)(-al / a0);
    cf[i * 4 + 2] = (double)(float)(-2.0 * cos(omega) / a0);
    cf[i * 4 + 3] = (double)(float)((1.0 - al) / a0);
}

// ---- fused-cascade zero-state pass: thread (j,m) -> v[m][j][8] ----
__global__ __launch_bounds__(256) void k_bqf_zero(const void* __restrict__ x,
        const double* __restrict__ cf, const int* __restrict__ flagp,
        double* __restrict__ v) {
    int i = blockIdx.x * 256 + threadIdx.x;
    if (i >= NMEL * NCHK) return;
    int isbf = *flagp;
    int j = i / NMEL, m = i % NMEL;
    double b0[4], b2[4], a1[4], a2[4];
#pragma unroll
    for (int s = 0; s < 4; ++s) {
        const double* c = &cf[(s * NMEL + m) * 4];
        b0[s] = c[0]; b2[s] = c[1]; a1[s] = c[2]; a2[s] = c[3];
    }
    int t0 = j * CHUNK;
    double x1 = (t0 > 0) ? ldd(isbf, x, t0 - 1) : 0.0;
    double x2 = (t0 > 1) ? ldd(isbf, x, t0 - 2) : 0.0;
    double s0 = 0, s1 = 0, s2 = 0, s3 = 0, s4 = 0, s5 = 0, s6 = 0, s7 = 0;
    for (int t = t0; t < t0 + CHUNK; ++t) {
        double xt = ldd(isbf, x, t);
        double y0 = fma(b0[0], xt, fma(b2[0], x2, fma(-a1[0], s0, -a2[0] * s1)));
        double y1 = fma(b0[1], y0, fma(b2[1], s1, fma(-a1[1], s2, -a2[1] * s3)));
        double y2 = fma(b0[2], y1, fma(b2[2], s3, fma(-a1[2], s4, -a2[2] * s5)));
        double y3 = fma(b0[3], y2, fma(b2[3], s5, fma(-a1[3], s6, -a2[3] * s7)));
        s1 = s0; s0 = y0; s3 = s2; s2 = y1; s5 = s4; s4 = y2; s7 = s6; s6 = y3;
        x2 = x1; x1 = xt;
    }
    double* vp = &v[((size_t)m * NCHK + j) * 8];
    vp[0] = s0; vp[1] = s1; vp[2] = s2; vp[3] = s3;
    vp[4] = s4; vp[5] = s5; vp[6] = s6; vp[7] = s7;
}

__global__ __launch_bounds__(256) void k_bqA(const double* __restrict__ cf,
                                             double* __restrict__ M) {
    __shared__ double P[4][8][8], R[4][8][8], T[4][8][8];
    int t = threadIdx.x;
    int cg = t >> 6, e8 = t & 63;
    int i = e8 >> 3, jj = e8 & 7;
    int m = blockIdx.x * 4 + cg;
    double b0[4], b2[4], a1[4], a2[4];
#pragma unroll
    for (int s = 0; s < 4; ++s) {
        const double* c = &cf[(s * NMEL + m) * 4];
        b0[s] = c[0]; b2[s] = c[1]; a1[s] = c[2]; a2[s] = c[3];
    }
    double s[8];
#pragma unroll
    for (int k = 0; k < 8; ++k) s[k] = (k == jj) ? 1.0 : 0.0;
    double y0 = fma(-a1[0], s[0], -a2[0] * s[1]);
    double y1 = fma(b0[1], y0, fma(b2[1], s[1], fma(-a1[1], s[2], -a2[1] * s[3])));
    double y2 = fma(b0[2], y1, fma(b2[2], s[3], fma(-a1[2], s[4], -a2[2] * s[5])));
    double y3 = fma(b0[3], y2, fma(b2[3], s[5], fma(-a1[3], s[6], -a2[3] * s[7])));
    double colv[8] = {y0, s[0], y1, s[2], y2, s[4], y3, s[6]};
    P[cg][i][jj] = colv[i];
    R[cg][i][jj] = (i == jj) ? 1.0 : 0.0;
    __syncthreads();
    int e = CHUNK;
    while (e) {
        double acc = 0.0;
#pragma unroll
        for (int k = 0; k < 8; ++k) acc = fma(R[cg][i][k], P[cg][k][jj], acc);
        T[cg][i][jj] = acc;
        __syncthreads();
        if (e & 1) R[cg][i][jj] = T[cg][i][jj];
        __syncthreads();
        acc = 0.0;
#pragma unroll
        for (int k = 0; k < 8; ++k) acc = fma(P[cg][i][k], P[cg][k][jj], acc);
        T[cg][i][jj] = acc;
        __syncthreads();
        P[cg][i][jj] = T[cg][i][jj];
        e >>= 1;
        __syncthreads();
    }
    M[(size_t)m * 64 + i * 8 + jj] = R[cg][i][jj];
}

// ---- Kogge-Stone parallel chunk scan (NCHK=400, 9 steps); block = channel ----
__global__ __launch_bounds__(512) void k_bq_scan8p(const double* __restrict__ Mbuf,
        const double* __restrict__ v, double* __restrict__ ini) {
    __shared__ double Mp[9][64];
    __shared__ double bufA[NCHK][8];
    __shared__ double bufB[NCHK][8];
    int m = blockIdx.x, t = threadIdx.x;
    if (t < 64) Mp[0][t] = Mbuf[(size_t)m * 64 + t];
    __syncthreads();
    for (int s = 1; s < 9; ++s) {
        if (t < 64) {
            int i = t >> 3, jj = t & 7;
            double acc = 0.0;
#pragma unroll
            for (int k = 0; k < 8; ++k) acc = fma(Mp[s - 1][i * 8 + k], Mp[s - 1][k * 8 + jj], acc);
            Mp[s][t] = acc;
        }
        __syncthreads();
    }
    double b[8];
    if (t < NCHK) {
        const double* vp = &v[((size_t)m * NCHK + t) * 8];
#pragma unroll
        for (int i = 0; i < 8; ++i) { b[i] = vp[i]; bufA[t][i] = b[i]; }
    }
    __syncthreads();
#pragma unroll
    for (int s = 0; s < 9; ++s) {
        int off = 1 << s;
        double nb[8];
        if (t < NCHK) {
            if (t >= off) {
                const double* src = (s & 1) ? bufB[t - off] : bufA[t - off];
#pragma unroll
                for (int i = 0; i < 8; ++i) {
                    double acc = b[i];
#pragma unroll
                    for (int k = 0; k < 8; ++k) acc = fma(Mp[s][i * 8 + k], src[k], acc);
                    nb[i] = acc;
                }
            } else {
#pragma unroll
                for (int i = 0; i < 8; ++i) nb[i] = b[i];
            }
        }
        __syncthreads();
        if (t < NCHK) {
            double* dst = (s & 1) ? bufA[t] : bufB[t];
#pragma unroll
            for (int i = 0; i < 8; ++i) { dst[i] = nb[i]; b[i] = nb[i]; }
        }
        __syncthreads();
    }
    if (t < NCHK) {
        double* op = &ini[((size_t)m * NCHK + t) * 8];
        if (t == 0) {
#pragma unroll
            for (int i = 0; i < 8; ++i) op[i] = 0.0;
        } else {
#pragma unroll
            for (int i = 0; i < 8; ++i) op[i] = bufB[t - 1][i];
        }
    }
}

// ---- fused-cascade emit: 1 frame/thread -> |y3| mean -> log -> feats ----
__global__ __launch_bounds__(256) void k_bqf_emit(const void* __restrict__ x,
        const double* __restrict__ cf, const int* __restrict__ flagp,
        const double* __restrict__ ini, float* __restrict__ feats) {
    int i = blockIdx.x * 256 + threadIdx.x;
    if (i >= NMEL * NCHK) return;
    int isbf = *flagp;
    int j = i / NMEL, m = i % NMEL;
    double b0[4], b2[4], a1[4], a2[4];
#pragma unroll
    for (int s = 0; s < 4; ++s) {
        const double* c = &cf[(s * NMEL + m) * 4];
        b0[s] = c[0]; b2[s] = c[1]; a1[s] = c[2]; a2[s] = c[3];
    }
    int t0 = j * CHUNK;
    double x1 = (t0 > 0) ? ldd(isbf, x, t0 - 1) : 0.0;
    double x2 = (t0 > 1) ? ldd(isbf, x, t0 - 2) : 0.0;
    const double* ip = &ini[((size_t)m * NCHK + j) * 8];
    double s0 = ip[0], s1 = ip[1], s2 = ip[2], s3 = ip[3];
    double s4 = ip[4], s5 = ip[5], s6 = ip[6], s7 = ip[7];
    double acc = 0.0;
    for (int t = t0; t < t0 + CHUNK; ++t) {
        double xt = ldd(isbf, x, t);
        double y0 = fma(b0[0], xt, fma(b2[0], x2, fma(-a1[0], s0, -a2[0] * s1)));
        double y1 = fma(b0[1], y0, fma(b2[1], s1, fma(-a1[1], s2, -a2[1] * s3)));
        double y2 = fma(b0[2], y1, fma(b2[2], s3, fma(-a1[2], s4, -a2[2] * s5)));
        double y3 = fma(b0[3], y2, fma(b2[3], s5, fma(-a1[3], s6, -a2[3] * s7)));
        acc += fabs(y3);
        s1 = s0; s0 = y0; s3 = s2; s2 = y1; s5 = s4; s4 = y2; s7 = s6; s6 = y3;
        x2 = x1; x1 = xt;
    }
    feats[(size_t)m * 400 + j] = (float)log(acc * (1.0 / 160.0) + 1e-8);
}

__global__ void k_fill0(bf16* __restrict__ p, int n8) {
    int i = blockIdx.x * 256 + threadIdx.x;
    if (i < n8) { s16x8 z = {}; ((s16x8*)p)[i] = z; }
}

__global__ void k_wtb(const void* __restrict__ w, const int* __restrict__ flagp,
                      bf16* __restrict__ out, int CO, int CIN) {
    int i = blockIdx.x * 256 + threadIdx.x;
    int K = CIN * 9;
    if (i >= CO * K) return;
    int co = i / K, rem = i % K;
    int c = rem / 288, tp = (rem / 32) % 9, cin = rem & 31;
    out[i] = __float2bfloat16(ldf(*flagp, w, ((size_t)co * CIN + c * 32 + cin) * 9 + tp));
}

__global__ __launch_bounds__(256) void k_conv1cl(const float* __restrict__ in,
        const void* __restrict__ wt, const void* __restrict__ bi,
        const void* __restrict__ ga, const void* __restrict__ be,
        const int* __restrict__ flagp, bf16* __restrict__ out) {
    __shared__ float wsh[576];
    __shared__ float ash[64];
    __shared__ float bsh[64];
    int t = threadIdx.x;
    int isbf = *flagp;
    for (int i = t; i < 576; i += 256) wsh[i] = ldf(isbf, wt, i);
    if (t < 64) {
        float A = ldf(isbf, ga, t) * 0.999995000037f;
        ash[t] = A;
        bsh[t] = fmaf(ldf(isbf, bi, t), A, ldf(isbf, be, t));
    }
    __syncthreads();
    int i = blockIdx.x * 256 + t;
    if (i >= 32000) return;
    int h = i / 400, w = i % 400;
    float xs[9];
#pragma unroll
    for (int dy = 0; dy < 3; ++dy)
#pragma unroll
        for (int dx = 0; dx < 3; ++dx) {
            int hh = h + dy - 1, ww = w + dx - 1;
            xs[dy * 3 + dx] = (hh >= 0 && hh < 80 && ww >= 0 && ww < 400)
                              ? in[hh * 400 + ww] : 0.f;
        }
    bf16* op = out + ((size_t)(h + 1) * CLW + (w + 1)) * 64;
#pragma unroll
    for (int g = 0; g < 8; ++g) {
        union { bf16 h8[8]; s16x8 v; } u;
#pragma unroll
        for (int e = 0; e < 8; ++e) {
            int co = g * 8 + e;
            float acc = 0.f;
#pragma unroll
            for (int uu = 0; uu < 9; ++uu) acc = fmaf(wsh[co * 9 + uu], xs[uu], acc);
            u.h8[e] = __float2bfloat16(fmaxf(fmaf(acc, ash[co], bsh[co]), 0.f));
        }
        *(s16x8*)&op[g * 8] = u.v;
    }
}

// ---- MFMA conv3x3, 2 output rows per block ----
template<int CIN, int CO, int CLOUT>
__global__ __launch_bounds__(256) void k_convm(const bf16* __restrict__ cl,
        const bf16* __restrict__ Wtb,
        const void* __restrict__ bi, const void* __restrict__ ga,
        const void* __restrict__ be, const int* __restrict__ flagp,
        void* __restrict__ out) {
    const int MT = CO / 64;
    const int K = CIN * 9;
    __shared__ short Bs[4][36][40];
    int t = threadIdx.x, wv = t >> 6, L = t & 63, quad = L >> 4, lx = L & 15;
    int w0 = blockIdx.x * 32, h0 = blockIdx.y * 2;
    int cob = wv * (CO / 4);
    f32x4 acc[MT][2][2] = {};     // [mt][hr][n]
    for (int c = 0; c < CIN / 32; ++c) {
        __syncthreads();
        for (int u = t; u < 544; u += 256) {
            int seg = u >> 2, part = u & 3;
            int dy = seg / 34, ww = seg % 34;
            *(s16x8*)&Bs[dy][ww][part * 8] =
                *(const s16x8*)&cl[((size_t)(h0 + dy) * CLW + (w0 + ww)) * CIN + c * 32 + part * 8];
        }
        __syncthreads();
#pragma unroll
        for (int tp = 0; tp < 9; ++tp) {
            int dy = tp / 3, dx = tp % 3;
            int kbase = (c * 9 + tp) * 32;
            s16x8 af[MT];
#pragma unroll
            for (int mt = 0; mt < MT; ++mt)
                af[mt] = *(const s16x8*)&Wtb[(size_t)(cob + mt * 16 + lx) * K + kbase + quad * 8];
#pragma unroll
            for (int hr = 0; hr < 2; ++hr) {
#pragma unroll
                for (int n = 0; n < 2; ++n) {
                    s16x8 bfr = *(const s16x8*)&Bs[dy + hr][n * 16 + lx + dx][quad * 8];
#pragma unroll
                    for (int mt = 0; mt < MT; ++mt)
                        acc[mt][hr][n] = __builtin_amdgcn_mfma_f32_16x16x32_bf16(af[mt], bfr, acc[mt][hr][n], 0, 0, 0);
                }
            }
        }
    }
    int isbf = *flagp;
#pragma unroll
    for (int mt = 0; mt < MT; ++mt) {
#pragma unroll
        for (int r = 0; r < 4; ++r) {
            int co = cob + mt * 16 + quad * 4 + r;
            float A = ldf(isbf, ga, co) * 0.999995000037f;
            float B = fmaf(ldf(isbf, bi, co), A, ldf(isbf, be, co));
#pragma unroll
            for (int hr = 0; hr < 2; ++hr) {
                int h = h0 + hr;
#pragma unroll
                for (int n = 0; n < 2; ++n) {
                    int w = w0 + n * 16 + lx;
                    if (w < 400) {
                        float v = fmaxf(fmaf(acc[mt][hr][n][r], A, B), 0.f);
                        if (CLOUT)
                            ((bf16*)out)[((size_t)(h + 1) * CLW + (w + 1)) * CO + co] = __float2bfloat16(v);
                        else
                            ((float*)out)[(size_t)co * 32000 + h * 400 + w] = v;
                    }
                }
            }
        }
    }
}

__global__ __launch_bounds__(256) void k_pool(const float* __restrict__ c3,
                                              float* __restrict__ tok) {
    int i = blockIdx.x * 256 + threadIdx.x;
    if (i >= SEQ * DMODEL) return;
    int s = i >> 8, c = i & 255;
    int f = s >> 5, jj = s & 31;
    int w0 = (jj * 25) >> 1;
    const float* p = c3 + ((size_t)c * 80 + f) * 400 + w0;
    float sum = 0.f;
#pragma unroll
    for (int k = 0; k < 13; ++k) sum += p[k];
    tok[i] = sum * (1.f / 13.f);
}

// ===== MFMA bf16 GEMM, chunked-K staging (KC=128) =====
// OUTMODE: 0 fp32 ; 1 flex ; 2 bf16 + V^T side-copy ; 3 always bf16. ABF16: A is bf16.
template<int RELU, int OUTMODE, int NT, int ACOMB, int ABF16>
__global__ __launch_bounds__(256) void k_gemm(const void* __restrict__ A,
        const void* __restrict__ W, size_t woff,
        const void* __restrict__ bias, size_t boff,
        const int* __restrict__ flagp, void* __restrict__ Cout_,
        bf16* __restrict__ vtb, const float* __restrict__ partb,
        int M, int N, int K) {
    __shared__ short As[64][136];
    __shared__ short Bs[NT * 16][136];
    const int isbf = *flagp;
    int t = threadIdx.x;
    int wv = t >> 6, L = t & 63, quad = L >> 4, lx = L & 15;
    int row0 = blockIdx.y * 64, col0 = blockIdx.x * (NT * 16);
    f32x4 acc[NT] = {};
    for (int k0 = 0; k0 < K; k0 += 128) {
        __syncthreads();
        {
            int row = t >> 2, cb = (t & 3) * 8;
#pragma unroll
            for (int c = 0; c < 4; ++c) {
                int col = cb + c * 32;
                s16x8 av;
                if (ACOMB) {
                    int q = row0 + row;
                    int kk = k0 + col;
                    int hh = kk >> 5, d = kk & 31;
                    const float* pa = partb + ((size_t)(hh * 2) * SEQ + q) * 36;
                    const float* pc = pa + (size_t)SEQ * 36;
                    float m0 = pa[32], l0 = pa[33], m1 = pc[32], l1 = pc[33];
                    float Mx = fmaxf(m0, m1);
                    float e0 = __expf(m0 - Mx), e1 = __expf(m1 - Mx);
                    float inv = 1.f / (l0 * e0 + l1 * e1);
                    float4 u0 = *(const float4*)(pa + d), u1 = *(const float4*)(pa + d + 4);
                    float4 v0 = *(const float4*)(pc + d), v1 = *(const float4*)(pc + d + 4);
                    float4 r0, r1;
                    r0.x = (u0.x * e0 + v0.x * e1) * inv; r0.y = (u0.y * e0 + v0.y * e1) * inv;
                    r0.z = (u0.z * e0 + v0.z * e1) * inv; r0.w = (u0.w * e0 + v0.w * e1) * inv;
                    r1.x = (u1.x * e0 + v1.x * e1) * inv; r1.y = (u1.y * e0 + v1.y * e1) * inv;
                    r1.z = (u1.z * e0 + v1.z * e1) * inv; r1.w = (u1.w * e0 + v1.w * e1) * inv;
                    av = cvt8(r0, r1);
                } else if (ABF16) {
                    av = *(const s16x8*)((const bf16*)A + (size_t)(row0 + row) * K + k0 + col);
                } else {
                    const float* ap = (const float*)A + (size_t)(row0 + row) * K + k0 + col;
                    av = cvt8(*(const float4*)ap, *(const float4*)(ap + 4));
                }
                *(s16x8*)&As[row][col] = av;
            }
        }
        if (NT == 4) {
            int row = t >> 2, cb = (t & 3) * 8;
#pragma unroll
            for (int c = 0; c < 4; ++c) {
                int col = cb + c * 32;
                size_t widx = woff + (size_t)(col0 + row) * K + k0 + col;
                s16x8 wv8;
                if (isbf) {
                    wv8 = *(const s16x8*)((const bf16*)W + widx);
                } else {
                    const float* wf = (const float*)W + widx;
                    wv8 = cvt8(*(const float4*)wf, *(const float4*)(wf + 4));
                }
                *(s16x8*)&Bs[row][col] = wv8;
            }
        } else {
            int row = t >> 3, cb = (t & 7) * 8;
#pragma unroll
            for (int c = 0; c < 2; ++c) {
                int col = cb + c * 64;
                size_t widx = woff + (size_t)(col0 + row) * K + k0 + col;
                s16x8 wv8;
                if (isbf) {
                    wv8 = *(const s16x8*)((const bf16*)W + widx);
                } else {
                    const float* wf = (const float*)W + widx;
                    wv8 = cvt8(*(const float4*)wf, *(const float4*)(wf + 4));
                }
                *(s16x8*)&Bs[row][col] = wv8;
            }
        }
        __syncthreads();
#pragma unroll
        for (int kc = 0; kc < 4; ++kc) {
            s16x8 af = *(const s16x8*)&As[wv * 16 + lx][kc * 32 + quad * 8];
#pragma unroll
            for (int n = 0; n < NT; ++n) {
                s16x8 bf_ = *(const s16x8*)&Bs[n * 16 + lx][kc * 32 + quad * 8];
                acc[n] = __builtin_amdgcn_mfma_f32_16x16x32_bf16(af, bf_, acc[n], 0, 0, 0);
            }
        }
    }
#pragma unroll
    for (int n = 0; n < NT; ++n) {
        int col = col0 + n * 16 + lx;
        float bv = ldf(isbf, bias, boff + col);
#pragma unroll
        for (int r = 0; r < 4; ++r) {
            int row = row0 + wv * 16 + quad * 4 + r;
            float val = acc[n][r] + bv;
            if (RELU) val = fmaxf(val, 0.f);
            if (OUTMODE == 0) {
                ((float*)Cout_)[(size_t)row * N + col] = val;
            } else if (OUTMODE == 2) {
                bf16 bb_ = __float2bfloat16(val);
                ((bf16*)Cout_)[(size_t)row * N + col] = bb_;
                if (col >= 512) vtb[(size_t)(col - 512) * SEQ + row] = bb_;
            } else if (OUTMODE == 3) {
                ((bf16*)Cout_)[(size_t)row * N + col] = __float2bfloat16(val);
            } else {
                if (isbf) ((bf16*)Cout_)[(size_t)row * N + col] = __float2bfloat16(val);
                else      ((float*)Cout_)[(size_t)row * N + col] = val;
            }
        }
    }
}

// ===== MFMA flash attention, KSPLIT=2; part rows stride 36 =====
__global__ __launch_bounds__(256) void k_flash(const bf16* __restrict__ qkvB,
        const bf16* __restrict__ vtb, float* __restrict__ part) {
    int b = blockIdx.x;
    int pp = b & 1, qb = (b >> 1) % 40, h = b / 80;
    int t = threadIdx.x, wv = t >> 6, L = t & 63, quad = L >> 4, lx = L & 15;
    int q0 = qb * 64;
    __shared__ short Qs[64][40];
    __shared__ short Ks[64][40];
    __shared__ short Vt[32][72];
    __shared__ short Ps[64][72];
    const float scale = 0.17677669529663687f;
    int sr = t >> 2, sk = (t & 3) * 8;
    *(s16x8*)&Qs[sr][sk] = *(const s16x8*)&qkvB[(size_t)(q0 + sr) * 768 + h * 32 + sk];
    f32x4 o[2] = {};
    float mrow[4], lrow[4];
#pragma unroll
    for (int r = 0; r < 4; ++r) { mrow[r] = -INFINITY; lrow[r] = 0.f; }
    int kstart = pp * 1280;
    int vd = t >> 3, vk = (t & 7) * 8;
    for (int kt = 0; kt < 20; ++kt) {
        int kb = kstart + kt * 64;
        __syncthreads();
        *(s16x8*)&Ks[sr][sk] = *(const s16x8*)&qkvB[(size_t)(kb + sr) * 768 + 256 + h * 32 + sk];
        *(s16x8*)&Vt[vd][vk] = *(const s16x8*)&vtb[(size_t)(h * 32 + vd) * SEQ + kb + vk];
        __syncthreads();
        s16x8 qf = *(const s16x8*)&Qs[wv * 16 + lx][quad * 8];
        f32x4 sc[4] = {};
#pragma unroll
        for (int n = 0; n < 4; ++n) {
            s16x8 kf = *(const s16x8*)&Ks[n * 16 + lx][quad * 8];
            sc[n] = __builtin_amdgcn_mfma_f32_16x16x32_bf16(qf, kf, sc[n], 0, 0, 0);
        }
#pragma unroll
        for (int r = 0; r < 4; ++r) {
            float tm = -INFINITY;
#pragma unroll
            for (int n = 0; n < 4; ++n) { sc[n][r] *= scale; tm = fmaxf(tm, sc[n][r]); }
#pragma unroll
            for (int mk = 1; mk < 16; mk <<= 1) tm = fmaxf(tm, __shfl_xor(tm, mk));
            float mn = fmaxf(mrow[r], tm);
            float al = __expf(mrow[r] - mn);
            float ps = 0.f;
#pragma unroll
            for (int n = 0; n < 4; ++n) {
                float e = __expf(sc[n][r] - mn);
                sc[n][r] = e; ps += e;
            }
#pragma unroll
            for (int mk = 1; mk < 16; mk <<= 1) ps += __shfl_xor(ps, mk);
            lrow[r] = lrow[r] * al + ps;
            mrow[r] = mn;
            o[0][r] *= al; o[1][r] *= al;
            int qrow = wv * 16 + quad * 4 + r;
#pragma unroll
            for (int n = 0; n < 4; ++n) Ps[qrow][n * 16 + lx] = sbf(sc[n][r]);
        }
        __syncthreads();
#pragma unroll
        for (int ks = 0; ks < 2; ++ks) {
            s16x8 pf = *(const s16x8*)&Ps[wv * 16 + lx][ks * 32 + quad * 8];
#pragma unroll
            for (int n = 0; n < 2; ++n) {
                s16x8 vf = *(const s16x8*)&Vt[n * 16 + lx][ks * 32 + quad * 8];
                o[n] = __builtin_amdgcn_mfma_f32_16x16x32_bf16(pf, vf, o[n], 0, 0, 0);
            }
        }
    }
#pragma unroll
    for (int r = 0; r < 4; ++r) {
        int q = q0 + wv * 16 + quad * 4 + r;
        size_t pb_ = ((size_t)(h * 2 + pp) * SEQ + q) * 36;
        part[pb_ + lx] = o[0][r];
        part[pb_ + 16 + lx] = o[1][r];
        if (lx == 0) { part[pb_ + 32] = mrow[r]; part[pb_ + 33] = lrow[r]; }
    }
}

__global__ __launch_bounds__(256) void k_ln(float* __restrict__ tok,
        const float* __restrict__ res, const void* __restrict__ gg,
        const void* __restrict__ bb, size_t goff, const int* __restrict__ flagp) {
    int isbf = *flagp;
    int row = blockIdx.x * 4 + (threadIdx.x >> 6);
    int lane = threadIdx.x & 63;
    float* tp = tok + (size_t)row * DMODEL;
    const float* rp = res + (size_t)row * DMODEL;
    float4 a = *(const float4*)&tp[lane * 4];
    float4 r = *(const float4*)&rp[lane * 4];
    float x0 = a.x + r.x, x1 = a.y + r.y, x2 = a.z + r.z, x3 = a.w + r.w;
    float s = x0 + x1 + x2 + x3;
#pragma unroll
    for (int mk = 1; mk < 64; mk <<= 1) s += __shfl_xor(s, mk);
    float mean = s * (1.f / 256.f);
    float d0 = x0 - mean, d1 = x1 - mean, d2 = x2 - mean, d3 = x3 - mean;
    float vs = d0 * d0 + d1 * d1 + d2 * d2 + d3 * d3;
#pragma unroll
    for (int mk = 1; mk < 64; mk <<= 1) vs += __shfl_xor(vs, mk);
    float rstd = rsqrtf(vs * (1.f / 256.f) + 1e-5f);
    size_t c = goff + lane * 4;
    float y0 = fmaf(d0 * rstd, ldf(isbf, gg, c + 0), ldf(isbf, bb, c + 0));
    float y1 = fmaf(d1 * rstd, ldf(isbf, gg, c + 1), ldf(isbf, bb, c + 1));
    float y2 = fmaf(d2 * rstd, ldf(isbf, gg, c + 2), ldf(isbf, bb, c + 2));
    float y3 = fmaf(d3 * rstd, ldf(isbf, gg, c + 3), ldf(isbf, bb, c + 3));
    *(float4*)&tp[lane * 4] = make_float4(y0, y1, y2, y3);
}

extern "C" void kernel_launch(void* const* d_in, const int* in_sizes, int n_in,
                              void* d_out, int out_size, void* d_ws, size_t ws_size,
                              hipStream_t stream) {
    const void* x    = d_in[0];
    const void* cw1  = d_in[1];  const void* cb1 = d_in[2];
    const void* g1   = d_in[3];  const void* be1 = d_in[4];
    const void* cw2  = d_in[5];  const void* cb2 = d_in[6];
    const void* g2   = d_in[7];  const void* be2 = d_in[8];
    const void* cw3  = d_in[9];  const void* cb3 = d_in[10];
    const void* g3   = d_in[11]; const void* be3 = d_in[12];
    const void* qkvw = d_in[13]; const void* qkvb = d_in[14];
    const void* outw = d_in[15]; const void* outb = d_in[16];
    const void* ln1g = d_in[17]; const void* ln1b = d_in[18];
    const void* ff1w = d_in[19]; const void* ff1b = d_in[20];
    const void* ff2w = d_in[21]; const void* ff2b = d_in[22];
    const void* ln2g = d_in[23]; const void* ln2b = d_in[24];
    const void* pw   = d_in[25]; const void* pb   = d_in[26];

    float*  ws    = (float*)d_ws;
    double* coef  = (double*)(ws + F_COEF);
    int*    flagp = (int*)(ws + F_FLAG);
    double* Mbuf  = (double*)(ws + F_M);
    double* vbuf  = (double*)(ws + F_V);
    double* ini   = (double*)(ws + F_INI);
    float*  feats = ws + F_FEATS;
    float*  tok   = ws + F_TOK;
    bf16*   c1cl  = (bf16*)(ws + F_BIG + O_C1CL);
    bf16*   c2cl  = (bf16*)(ws + F_BIG + O_C2CL);
    float*  c3    = ws + F_BIG + O_C3;
    bf16*   Wtb2  = (bf16*)(ws + F_BIG + O_WTB2);
    bf16*   Wtb3  = (bf16*)(ws + F_BIG + O_WTB3);
    bf16*   qkvB  = (bf16*)(ws + F_BIG);
    bf16*   vtb   = (bf16*)(ws + F_BIG + 983040ul);
    float*  partb = ws + F_BIG + 1310720ul;
    float*  proj  = ws + F_BIG + 2785280ul;            // 655,360 f
    bf16*   ff1bf = (bf16*)(ws + F_BIG + 3440640ul);   // 2560x1024 bf16

    k_detect<<<dim3(1), dim3(64), 0, stream>>>((const unsigned short*)ln1g, flagp);
    k_coeffs<<<dim3(2), dim3(256), 0, stream>>>(coef);
    k_wtb<<<dim3(288), dim3(256), 0, stream>>>(cw2, flagp, Wtb2, 128, 64);
    k_wtb<<<dim3(1152), dim3(256), 0, stream>>>(cw3, flagp, Wtb3, 256, 128);

    // ---- cochlear cascade (fp64), CHUNK = one frame ----
    k_bqA<<<dim3(20), dim3(256), 0, stream>>>(coef, Mbuf);
    k_bqf_zero<<<dim3(125), dim3(256), 0, stream>>>(x, coef, flagp, vbuf);
    k_bq_scan8p<<<dim3(80), dim3(512), 0, stream>>>(Mbuf, vbuf, ini);
    k_bqf_emit<<<dim3(125), dim3(256), 0, stream>>>(x, coef, flagp, ini, feats);

    // ---- conv stack (channels-last MFMA, 2 rows/block) ----
    k_fill0<<<dim3(1077), dim3(256), 0, stream>>>(c1cl, 275520);
    k_fill0<<<dim3(2153), dim3(256), 0, stream>>>(c2cl, 551040);
    k_conv1cl<<<dim3(125), dim3(256), 0, stream>>>(feats, cw1, cb1, g1, be1, flagp, c1cl);
    k_convm<64, 128, 1><<<dim3(13, 40), dim3(256), 0, stream>>>(
        c1cl, Wtb2, cb2, g2, be2, flagp, c2cl);
    k_convm<128, 256, 0><<<dim3(13, 40), dim3(256), 0, stream>>>(
        c2cl, Wtb3, cb3, g3, be3, flagp, c3);

    k_pool<<<dim3(2560), dim3(256), 0, stream>>>(c3, tok);

    // ---- transformer encoder x8 (MFMA bf16; R10 structure + bf16 ff1 path) ----
    for (int l = 0; l < 8; ++l) {
        k_gemm<0, 2, 4, 0, 0><<<dim3(12, 40), dim3(256), 0, stream>>>(
            tok, qkvw, (size_t)l * 768 * 256, qkvb, (size_t)l * 768,
            flagp, qkvB, vtb, nullptr, SEQ, 768, 256);
        k_flash<<<dim3(640), dim3(256), 0, stream>>>(qkvB, vtb, partb);
        k_gemm<0, 0, 2, 1, 0><<<dim3(8, 40), dim3(256), 0, stream>>>(
            nullptr, outw, (size_t)l * 256 * 256, outb, (size_t)l * 256,
            flagp, proj, nullptr, partb, SEQ, 256, 256);
        k_ln<<<dim3(640), dim3(256), 0, stream>>>(tok, proj, ln1g, ln1b, (size_t)l * 256, flagp);
        k_gemm<1, 3, 4, 0, 0><<<dim3(16, 40), dim3(256), 0, stream>>>(
            tok, ff1w, (size_t)l * 1024 * 256, ff1b, (size_t)l * 1024,
            flagp, ff1bf, nullptr, nullptr, SEQ, 1024, 256);
        k_gemm<0, 0, 2, 0, 1><<<dim3(8, 40), dim3(256), 0, stream>>>(
            ff1bf, ff2w, (size_t)l * 256 * 1024, ff2b, (size_t)l * 256,
            flagp, proj, nullptr, nullptr, SEQ, 256, 1024);
        k_ln<<<dim3(640), dim3(256), 0, stream>>>(tok, proj, ln2g, ln2b, (size_t)l * 256, flagp);
    }

    k_gemm<0, 1, 2, 0, 0><<<dim3(16, 40), dim3(256), 0, stream>>>(
        tok, pw, 0ul, pb, 0ul, flagp, d_out, nullptr, nullptr, SEQ, 512, 256);
}